// Round 3
// baseline (600.388 us; speedup 1.0000x reference)
//
#include <hip/hip_runtime.h>

// GCN 2-layer forward: out = A( relu(A(X@W1)+b1) @ W2 ) + b2
// where A is sym-normalized adjacency with self loops.
// CSR build: count -> hierarchical scan -> 2-pass bucket scatter (write-traffic
// friendly). Each layer: LDS-tiled vector-fp32 GEMM + gather-aggregate.

__global__ __launch_bounds__(256) void init_deg_kernel(int* __restrict__ deg, int n) {
    int i = blockIdx.x * 256 + threadIdx.x;
    if (i < n) deg[i] = 1;   // self loop
}

__global__ __launch_bounds__(256) void count_kernel(const int* __restrict__ col,
                                                    int* __restrict__ deg, int E) {
    int i = blockIdx.x * 256 + threadIdx.x;
    if (i < E) atomicAdd(&deg[col[i]], 1);
}

// Phase 1: per-block sums of (deg[i]-1).
__global__ __launch_bounds__(256) void blocksum_kernel(const int* __restrict__ deg,
                                                       int* __restrict__ bsum, int N) {
    int i = blockIdx.x * 256 + threadIdx.x;
    int v = (i < N) ? deg[i] - 1 : 0;
#pragma unroll
    for (int o = 32; o > 0; o >>= 1) v += __shfl_down(v, o, 64);
    __shared__ int ws[4];
    if ((threadIdx.x & 63) == 0) ws[threadIdx.x >> 6] = v;
    __syncthreads();
    if (threadIdx.x == 0) bsum[blockIdx.x] = ws[0] + ws[1] + ws[2] + ws[3];
}

// Phase 2: single-block exclusive scan of <=1024 block sums; total -> *offN.
__global__ __launch_bounds__(1024) void bscan_kernel(const int* __restrict__ bsum,
                                                     int* __restrict__ boff,
                                                     int* __restrict__ offN, int nb) {
    __shared__ int s[1024];
    int t = threadIdx.x;
    int v = (t < nb) ? bsum[t] : 0;
    s[t] = v;
    __syncthreads();
    for (int d = 1; d < 1024; d <<= 1) {
        int u = (t >= d) ? s[t - d] : 0;
        __syncthreads();
        s[t] += u;
        __syncthreads();
    }
    if (t < nb) boff[t] = s[t] - v;           // exclusive
    if (t == nb - 1) *offN = s[t];            // total = E
}

// Phase 3: per-block exclusive scan of (deg-1) + block offset -> off/dis,
// plus per-64-node bucket cursors (bcur[b] = off[b*64]).
__global__ __launch_bounds__(256) void offsets_kernel(const int* __restrict__ deg,
                                                      const int* __restrict__ boff,
                                                      int* __restrict__ off,
                                                      int* __restrict__ bcur,
                                                      float* __restrict__ dis, int N) {
    int i = blockIdx.x * 256 + threadIdx.x;
    int lane = threadIdx.x & 63;
    int w = threadIdx.x >> 6;
    int d = (i < N) ? deg[i] - 1 : 0;
    int v = d;
#pragma unroll
    for (int o = 1; o < 64; o <<= 1) {
        int u = __shfl_up(v, o, 64);
        if (lane >= o) v += u;
    }
    __shared__ int ws[4];
    __shared__ int wo[4];
    if (lane == 63) ws[w] = v;
    __syncthreads();
    if (threadIdx.x == 0) {
        int r = 0;
#pragma unroll
        for (int k = 0; k < 4; ++k) { wo[k] = r; r += ws[k]; }
    }
    __syncthreads();
    if (i < N) {
        int excl = boff[blockIdx.x] + wo[w] + v - d;
        off[i] = excl;
        dis[i] = rsqrtf((float)deg[i]);
        if ((i & 63) == 0) bcur[i >> 6] = excl;
    }
}

// Pass A: bucket edges by col>>6. Per-bucket cursor advances sequentially, so
// the pairs[] writes stream per-bucket (full cacheline utilization in L2).
__global__ __launch_bounds__(256) void bucket_fill_kernel(const int* __restrict__ row,
                                                          const int* __restrict__ col,
                                                          int* __restrict__ bcur,
                                                          int2* __restrict__ pairs, int E) {
    int i = blockIdx.x * 256 + threadIdx.x;
    if (i < E) {
        int c = col[i];
        int s = row[i];
        int p = atomicAdd(&bcur[c >> 6], 1);
        pairs[p] = make_int2(s, c);
    }
}

// Pass B: one workgroup per 64-node bucket. Coalesced-read the bucket's pairs,
// LDS-scatter to exact per-node positions, coalesced-write csr.
__global__ __launch_bounds__(256) void place_kernel(const int2* __restrict__ pairs,
                                                    const int* __restrict__ off,
                                                    int* __restrict__ csr, int N) {
    constexpr int CAP = 4096;
    __shared__ int lcur[64];
    __shared__ int lout[CAP];
    int b = blockIdx.x;
    int n0 = b * 64;
    int n1 = min(n0 + 64, N);
    int base = off[n0];
    int cnt = off[n1] - base;
    if (threadIdx.x < 64) {
        int j = n0 + threadIdx.x;
        lcur[threadIdx.x] = (j < n1) ? off[j] - base : 0;
    }
    __syncthreads();
    for (int t = threadIdx.x; t < cnt; t += 256) {
        int2 pr = pairs[base + t];
        int lp = atomicAdd(&lcur[pr.y - n0], 1);
        if (lp < CAP) lout[lp] = pr.x;
        else csr[base + lp] = pr.x;          // overflow fallback (still exact pos)
    }
    __syncthreads();
    int staged = min(cnt, CAP);
    for (int t = threadIdx.x; t < staged; t += 256) csr[base + t] = lout[t];
}

// Y[M,TN] = X[M,128] @ W[128,TN].  Tile: 64 rows x TN cols, K-chunks of 32.
template<int TN>
__global__ __launch_bounds__(256) void gemm_kernel(const float* __restrict__ X,
                                                   const float* __restrict__ W,
                                                   float* __restrict__ Y, int M) {
    constexpr int K = 128, KC = 32, TM = 64;
    constexpr int CPT = TN / 16;                 // cols per thread: 8 (TN=128) / 4 (TN=64)
    __shared__ float As[KC][TM + 8];
    __shared__ float Bs[KC][TN];
    int tid = threadIdx.x;
    int row0 = blockIdx.x * TM;
    int tx = tid & 15, ty = tid >> 4;            // 16x16 thread grid
    float acc[4][CPT];
#pragma unroll
    for (int i = 0; i < 4; ++i)
#pragma unroll
        for (int j = 0; j < CPT; ++j) acc[i][j] = 0.0f;

    for (int k0 = 0; k0 < K; k0 += KC) {
#pragma unroll
        for (int j = 0; j < 2; ++j) {
            int l = tid + 256 * j;               // 0..511
            int r = l >> 3;
            int kq = l & 7;
            int row = row0 + r;
            float4 v = make_float4(0.f, 0.f, 0.f, 0.f);
            if (row < M) v = *(const float4*)(X + (size_t)row * K + k0 + kq * 4);
            As[kq * 4 + 0][r] = v.x;
            As[kq * 4 + 1][r] = v.y;
            As[kq * 4 + 2][r] = v.z;
            As[kq * 4 + 3][r] = v.w;
        }
#pragma unroll
        for (int j = 0; j < KC * TN / 1024; ++j) {
            int l = tid + 256 * j;
            int kk = l / (TN / 4);
            int cq = l % (TN / 4);
            *(float4*)&Bs[kk][cq * 4] = *(const float4*)(W + (size_t)(k0 + kk) * TN + cq * 4);
        }
        __syncthreads();
#pragma unroll
        for (int kk = 0; kk < KC; ++kk) {
            float4 av = *(const float4*)&As[kk][ty * 4];
            float a[4] = {av.x, av.y, av.z, av.w};
            float b[CPT];
#pragma unroll
            for (int q = 0; q < CPT / 4; ++q) {
                float4 bv = *(const float4*)&Bs[kk][tx * CPT + q * 4];
                b[q * 4 + 0] = bv.x; b[q * 4 + 1] = bv.y;
                b[q * 4 + 2] = bv.z; b[q * 4 + 3] = bv.w;
            }
#pragma unroll
            for (int i = 0; i < 4; ++i)
#pragma unroll
                for (int j = 0; j < CPT; ++j) acc[i][j] = fmaf(a[i], b[j], acc[i][j]);
        }
        __syncthreads();
    }
#pragma unroll
    for (int i = 0; i < 4; ++i) {
        int row = row0 + ty * 4 + i;
        if (row < M) {
#pragma unroll
            for (int q = 0; q < CPT / 4; ++q) {
                float4 v = make_float4(acc[i][q * 4], acc[i][q * 4 + 1],
                                       acc[i][q * 4 + 2], acc[i][q * 4 + 3]);
                *(float4*)(Y + (size_t)row * TN + tx * CPT + q * 4) = v;
            }
        }
    }
}

// out[v] = sum_{e: col=v} dis[src]*dis[v]*H[src] + dis[v]^2*H[v] + b, opt relu.
// One wave (64 lanes) per node; 4 nodes per 256-thread block.
template<int C, bool RELU>
__global__ __launch_bounds__(256) void agg_kernel(const float* __restrict__ H,
                                                  const int* __restrict__ off,
                                                  const int* __restrict__ src,
                                                  const float* __restrict__ dis,
                                                  const float* __restrict__ bias,
                                                  float* __restrict__ out, int N) {
    int node = blockIdx.x * 4 + (threadIdx.x >> 6);
    if (node >= N) return;
    int lane = threadIdx.x & 63;
    constexpr int F = C / 64;                    // floats per lane (2 or 1)
    float dv = dis[node];
    float acc[F];
    {
        const float* hp = H + (size_t)node * C + lane * F;
        float sw = dv * dv;
#pragma unroll
        for (int f = 0; f < F; ++f) acc[f] = sw * hp[f];
    }
    int e = off[node], e1 = off[node + 1];
    for (; e + 4 <= e1; e += 4) {
        int s0 = src[e + 0], s1 = src[e + 1], s2 = src[e + 2], s3 = src[e + 3];
        float w0 = dis[s0] * dv, w1 = dis[s1] * dv, w2 = dis[s2] * dv, w3 = dis[s3] * dv;
        const float* p0 = H + (size_t)s0 * C + lane * F;
        const float* p1 = H + (size_t)s1 * C + lane * F;
        const float* p2 = H + (size_t)s2 * C + lane * F;
        const float* p3 = H + (size_t)s3 * C + lane * F;
        if constexpr (F == 2) {
            float2 v0 = *(const float2*)p0, v1 = *(const float2*)p1;
            float2 v2 = *(const float2*)p2, v3 = *(const float2*)p3;
            acc[0] = fmaf(w0, v0.x, acc[0]); acc[1] = fmaf(w0, v0.y, acc[1]);
            acc[0] = fmaf(w1, v1.x, acc[0]); acc[1] = fmaf(w1, v1.y, acc[1]);
            acc[0] = fmaf(w2, v2.x, acc[0]); acc[1] = fmaf(w2, v2.y, acc[1]);
            acc[0] = fmaf(w3, v3.x, acc[0]); acc[1] = fmaf(w3, v3.y, acc[1]);
        } else {
            acc[0] = fmaf(w0, p0[0], acc[0]);
            acc[0] = fmaf(w1, p1[0], acc[0]);
            acc[0] = fmaf(w2, p2[0], acc[0]);
            acc[0] = fmaf(w3, p3[0], acc[0]);
        }
    }
    for (; e < e1; ++e) {
        int s = src[e];
        float w = dis[s] * dv;
        const float* p = H + (size_t)s * C + lane * F;
#pragma unroll
        for (int f = 0; f < F; ++f) acc[f] = fmaf(w, p[f], acc[f]);
    }
    float* op = out + (size_t)node * C + lane * F;
#pragma unroll
    for (int f = 0; f < F; ++f) {
        float v = acc[f] + bias[lane * F + f];
        op[f] = RELU ? fmaxf(v, 0.0f) : v;
    }
}

extern "C" void kernel_launch(void* const* d_in, const int* in_sizes, int n_in,
                              void* d_out, int out_size, void* d_ws, size_t ws_size,
                              hipStream_t stream) {
    const float* x  = (const float*)d_in[0];
    const int*   ei = (const int*)d_in[1];
    const float* W1 = (const float*)d_in[2];
    const float* b1 = (const float*)d_in[3];
    const float* W2 = (const float*)d_in[4];
    const float* b2 = (const float*)d_in[5];
    float* out = (float*)d_out;

    int N = in_sizes[0] / 128;
    int E = in_sizes[1] / 2;
    const int* row = ei;        // edge_index[0] = sources
    const int* col = ei + E;    // edge_index[1] = targets
    int nblk = (N + 255) / 256;
    int nbuck = (N + 63) / 64;

    char* ws = (char*)d_ws;
    size_t o = 0;
    auto alloc = [&](size_t bytes) -> void* {
        void* p = ws + o;
        o = (o + bytes + 255) & ~(size_t)255;
        return p;
    };
    int*   deg  = (int*)alloc((size_t)N * 4);
    int*   off  = (int*)alloc((size_t)(N + 1) * 4);
    float* dis  = (float*)alloc((size_t)N * 4);
    int*   csr  = (int*)alloc((size_t)E * 4);
    int*   bsum = (int*)alloc((size_t)nblk * 4);
    int*   boff = (int*)alloc((size_t)nblk * 4);
    int*   bcur = (int*)alloc((size_t)nbuck * 4);
    float* xw   = (float*)alloc((size_t)N * 128 * 4);
    float* h    = (float*)alloc((size_t)N * 128 * 4);
    int2*  pairs = (int2*)xw;   // alias: pairs dead before gemm1 writes xw
    float* hw2   = xw;          // alias: layer-2 GEMM output (64 cols)

    init_deg_kernel<<<nblk, 256, 0, stream>>>(deg, N);
    count_kernel<<<(E + 255) / 256, 256, 0, stream>>>(col, deg, E);
    blocksum_kernel<<<nblk, 256, 0, stream>>>(deg, bsum, N);
    bscan_kernel<<<1, 1024, 0, stream>>>(bsum, boff, &off[N], nblk);
    offsets_kernel<<<nblk, 256, 0, stream>>>(deg, boff, off, bcur, dis, N);
    bucket_fill_kernel<<<(E + 255) / 256, 256, 0, stream>>>(row, col, bcur, pairs, E);
    place_kernel<<<nbuck, 256, 0, stream>>>(pairs, off, csr, N);

    gemm_kernel<128><<<(N + 63) / 64, 256, 0, stream>>>(x, W1, xw, N);
    agg_kernel<128, true><<<(N + 3) / 4, 256, 0, stream>>>(xw, off, csr, dis, b1, h, N);
    gemm_kernel<64><<<(N + 63) / 64, 256, 0, stream>>>(h, W2, hw2, N);
    agg_kernel<64, false><<<(N + 3) / 4, 256, 0, stream>>>(hw2, off, csr, dis, b2, out, N);
}

// Round 4
// 349.448 us; speedup vs baseline: 1.7181x; 1.7181x over previous
//
#include <hip/hip_runtime.h>

// GCN 2-layer forward: out = A( relu(A(X@W1)+b1) @ W2 ) + b2
// where A is sym-normalized adjacency with self loops.
// CSR build via 2-level LDS-staged binning (all global writes are contiguous
// runs flushed from LDS by one workgroup — no partial-cacheline scatter).
// Each layer: LDS-tiled vector-fp32 GEMM + gather-aggregate.

constexpr int BSH = 9;              // 512 nodes per bucket
constexpr int BNODES = 1 << BSH;
constexpr int CHUNK = 4096;         // edges per scatter block
constexpr int CAP = 12288;          // place LDS staging capacity (mean ~8200)

__global__ __launch_bounds__(256) void zero_kernel(int* __restrict__ p, int n) {
    int i = blockIdx.x * 256 + threadIdx.x;
    if (i < n) p[i] = 0;
}

// Per-bucket edge histogram (LDS-staged).
__global__ __launch_bounds__(256) void hist_kernel(const int* __restrict__ col,
                                                   int* __restrict__ bhist,
                                                   int E, int NB) {
    __shared__ int lh[256];
    int t = threadIdx.x;
    lh[t] = 0;
    __syncthreads();
    for (int i = blockIdx.x * 256 + t; i < E; i += gridDim.x * 256)
        atomicAdd(&lh[col[i] >> BSH], 1);
    __syncthreads();
    if (t < NB && lh[t]) atomicAdd(&bhist[t], lh[t]);
}

// Exclusive scan of NB (<=256) bucket counts -> bbase[0..NB], bcur.
__global__ __launch_bounds__(256) void bbase_scan_kernel(const int* __restrict__ bhist,
                                                         int* __restrict__ bbase,
                                                         int* __restrict__ bcur, int NB) {
    __shared__ int s[256];
    int t = threadIdx.x;
    int v = (t < NB) ? bhist[t] : 0;
    s[t] = v;
    __syncthreads();
    for (int d = 1; d < 256; d <<= 1) {
        int u = (t >= d) ? s[t - d] : 0;
        __syncthreads();
        s[t] += u;
        __syncthreads();
    }
    if (t < NB) { bbase[t] = s[t] - v; bcur[t] = s[t] - v; }
    if (t == NB - 1) bbase[NB] = s[t];
}

// Partition edges into bucket-grouped pairs[]. One atomic reservation per
// (block,bucket); all global writes are contiguous runs from LDS.
__global__ __launch_bounds__(256) void bucket_scatter_kernel(const int* __restrict__ row,
                                                             const int* __restrict__ col,
                                                             int* __restrict__ bcur,
                                                             int2* __restrict__ pairs,
                                                             int E, int NB) {
    __shared__ int2 sp[CHUNK];
    __shared__ int lhist[256], lofs[256], lcur[256], gbase[256];
    int t = threadIdx.x;
    int start = blockIdx.x * CHUNK;
    int cnt = min(CHUNK, E - start);
    lhist[t] = 0;
    __syncthreads();
    for (int i = t; i < cnt; i += 256)
        atomicAdd(&lhist[col[start + i] >> BSH], 1);
    __syncthreads();
    int v = lhist[t];
    lofs[t] = v;
    __syncthreads();
    for (int d = 1; d < 256; d <<= 1) {
        int u = (t >= d) ? lofs[t - d] : 0;
        __syncthreads();
        lofs[t] += u;
        __syncthreads();
    }
    int excl = lofs[t] - v;            // exclusive local offset of bucket t
    lofs[t] = excl;
    lcur[t] = excl;
    if (t < NB && v > 0) gbase[t] = atomicAdd(&bcur[t], v);
    __syncthreads();
    for (int i = t; i < cnt; i += 256) {
        int c = col[start + i];
        int s = row[start + i];
        int lp = atomicAdd(&lcur[c >> BSH], 1);
        sp[lp] = make_int2(s, c);
    }
    __syncthreads();
    for (int i = t; i < cnt; i += 256) {
        int2 pr = sp[i];
        int b = pr.y >> BSH;
        pairs[gbase[b] + (i - lofs[b])] = pr;
    }
}

// One block per bucket: per-node LDS histogram -> local scan gives off[] and
// dis[] directly; exact LDS placement; coalesced csr flush.
__global__ __launch_bounds__(256) void place_kernel(const int2* __restrict__ pairs,
                                                    const int* __restrict__ bbase,
                                                    int* __restrict__ off,
                                                    float* __restrict__ dis,
                                                    int* __restrict__ csr, int N, int NB) {
    __shared__ int lhist[BNODES], lexcl[BNODES], lcur2[BNODES];
    __shared__ int sscan[256];
    __shared__ int lout[CAP];
    int b = blockIdx.x;
    int t = threadIdx.x;
    int n0 = b << BSH;
    int n1 = min(n0 + BNODES, N);
    int nn = n1 - n0;
    int base = bbase[b];
    int cnt = bbase[b + 1] - base;
    lhist[2 * t] = 0;
    lhist[2 * t + 1] = 0;
    __syncthreads();
    for (int i = t; i < cnt; i += 256)
        atomicAdd(&lhist[pairs[base + i].y - n0], 1);
    __syncthreads();
    // scan 512 node-counts with 256 threads (pairwise + Hillis-Steele)
    int a0 = lhist[2 * t], a1 = lhist[2 * t + 1];
    int ps = a0 + a1;
    sscan[t] = ps;
    __syncthreads();
    for (int d = 1; d < 256; d <<= 1) {
        int u = (t >= d) ? sscan[t - d] : 0;
        __syncthreads();
        sscan[t] += u;
        __syncthreads();
    }
    int pexcl = sscan[t] - ps;
    lexcl[2 * t] = pexcl;
    lexcl[2 * t + 1] = pexcl + a0;
    lcur2[2 * t] = pexcl;
    lcur2[2 * t + 1] = pexcl + a0;
    __syncthreads();
    for (int i = t; i < nn; i += 256) {
        off[n0 + i] = base + lexcl[i];
        dis[n0 + i] = rsqrtf((float)(lhist[i] + 1));   // +1 self loop
    }
    if (b == NB - 1 && t == 0) off[N] = base + cnt;
    for (int i = t; i < cnt; i += 256) {
        int2 pr = pairs[base + i];
        int lp = atomicAdd(&lcur2[pr.y - n0], 1);
        if (lp < CAP) lout[lp] = pr.x;
        else csr[base + lp] = pr.x;        // overflow fallback (exact pos)
    }
    __syncthreads();
    int staged = min(cnt, CAP);
    for (int i = t; i < staged; i += 256) csr[base + i] = lout[i];
}

// Y[M,TN] = X[M,128] @ W[128,TN].  Tile: 64 rows x TN cols, K-chunks of 32.
template<int TN>
__global__ __launch_bounds__(256) void gemm_kernel(const float* __restrict__ X,
                                                   const float* __restrict__ W,
                                                   float* __restrict__ Y, int M) {
    constexpr int K = 128, KC = 32, TM = 64;
    constexpr int CPT = TN / 16;
    __shared__ float As[KC][TM + 8];
    __shared__ float Bs[KC][TN];
    int tid = threadIdx.x;
    int row0 = blockIdx.x * TM;
    int tx = tid & 15, ty = tid >> 4;
    float acc[4][CPT];
#pragma unroll
    for (int i = 0; i < 4; ++i)
#pragma unroll
        for (int j = 0; j < CPT; ++j) acc[i][j] = 0.0f;

    for (int k0 = 0; k0 < K; k0 += KC) {
#pragma unroll
        for (int j = 0; j < 2; ++j) {
            int l = tid + 256 * j;
            int r = l >> 3;
            int kq = l & 7;
            int row = row0 + r;
            float4 v = make_float4(0.f, 0.f, 0.f, 0.f);
            if (row < M) v = *(const float4*)(X + (size_t)row * K + k0 + kq * 4);
            As[kq * 4 + 0][r] = v.x;
            As[kq * 4 + 1][r] = v.y;
            As[kq * 4 + 2][r] = v.z;
            As[kq * 4 + 3][r] = v.w;
        }
#pragma unroll
        for (int j = 0; j < KC * TN / 1024; ++j) {
            int l = tid + 256 * j;
            int kk = l / (TN / 4);
            int cq = l % (TN / 4);
            *(float4*)&Bs[kk][cq * 4] = *(const float4*)(W + (size_t)(k0 + kk) * TN + cq * 4);
        }
        __syncthreads();
#pragma unroll
        for (int kk = 0; kk < KC; ++kk) {
            float4 av = *(const float4*)&As[kk][ty * 4];
            float a[4] = {av.x, av.y, av.z, av.w};
            float b[CPT];
#pragma unroll
            for (int q = 0; q < CPT / 4; ++q) {
                float4 bv = *(const float4*)&Bs[kk][tx * CPT + q * 4];
                b[q * 4 + 0] = bv.x; b[q * 4 + 1] = bv.y;
                b[q * 4 + 2] = bv.z; b[q * 4 + 3] = bv.w;
            }
#pragma unroll
            for (int i = 0; i < 4; ++i)
#pragma unroll
                for (int j = 0; j < CPT; ++j) acc[i][j] = fmaf(a[i], b[j], acc[i][j]);
        }
        __syncthreads();
    }
#pragma unroll
    for (int i = 0; i < 4; ++i) {
        int row = row0 + ty * 4 + i;
        if (row < M) {
#pragma unroll
            for (int q = 0; q < CPT / 4; ++q) {
                float4 v = make_float4(acc[i][q * 4], acc[i][q * 4 + 1],
                                       acc[i][q * 4 + 2], acc[i][q * 4 + 3]);
                *(float4*)(Y + (size_t)row * TN + tx * CPT + q * 4) = v;
            }
        }
    }
}

// out[v] = sum_{e: col=v} dis[src]*dis[v]*H[src] + dis[v]^2*H[v] + b, opt relu.
// One wave per node; 4 nodes per 256-thread block.
template<int C, bool RELU>
__global__ __launch_bounds__(256) void agg_kernel(const float* __restrict__ H,
                                                  const int* __restrict__ off,
                                                  const int* __restrict__ src,
                                                  const float* __restrict__ dis,
                                                  const float* __restrict__ bias,
                                                  float* __restrict__ out, int N) {
    int node = blockIdx.x * 4 + (threadIdx.x >> 6);
    if (node >= N) return;
    int lane = threadIdx.x & 63;
    constexpr int F = C / 64;
    float dv = dis[node];
    float acc[F];
    {
        const float* hp = H + (size_t)node * C + lane * F;
        float sw = dv * dv;
#pragma unroll
        for (int f = 0; f < F; ++f) acc[f] = sw * hp[f];
    }
    int e = off[node], e1 = off[node + 1];
    for (; e + 4 <= e1; e += 4) {
        int s0 = src[e + 0], s1 = src[e + 1], s2 = src[e + 2], s3 = src[e + 3];
        float w0 = dis[s0] * dv, w1 = dis[s1] * dv, w2 = dis[s2] * dv, w3 = dis[s3] * dv;
        const float* p0 = H + (size_t)s0 * C + lane * F;
        const float* p1 = H + (size_t)s1 * C + lane * F;
        const float* p2 = H + (size_t)s2 * C + lane * F;
        const float* p3 = H + (size_t)s3 * C + lane * F;
        if constexpr (F == 2) {
            float2 v0 = *(const float2*)p0, v1 = *(const float2*)p1;
            float2 v2 = *(const float2*)p2, v3 = *(const float2*)p3;
            acc[0] = fmaf(w0, v0.x, acc[0]); acc[1] = fmaf(w0, v0.y, acc[1]);
            acc[0] = fmaf(w1, v1.x, acc[0]); acc[1] = fmaf(w1, v1.y, acc[1]);
            acc[0] = fmaf(w2, v2.x, acc[0]); acc[1] = fmaf(w2, v2.y, acc[1]);
            acc[0] = fmaf(w3, v3.x, acc[0]); acc[1] = fmaf(w3, v3.y, acc[1]);
        } else {
            acc[0] = fmaf(w0, p0[0], acc[0]);
            acc[0] = fmaf(w1, p1[0], acc[0]);
            acc[0] = fmaf(w2, p2[0], acc[0]);
            acc[0] = fmaf(w3, p3[0], acc[0]);
        }
    }
    for (; e < e1; ++e) {
        int s = src[e];
        float w = dis[s] * dv;
        const float* p = H + (size_t)s * C + lane * F;
#pragma unroll
        for (int f = 0; f < F; ++f) acc[f] = fmaf(w, p[f], acc[f]);
    }
    float* op = out + (size_t)node * C + lane * F;
#pragma unroll
    for (int f = 0; f < F; ++f) {
        float v = acc[f] + bias[lane * F + f];
        op[f] = RELU ? fmaxf(v, 0.0f) : v;
    }
}

extern "C" void kernel_launch(void* const* d_in, const int* in_sizes, int n_in,
                              void* d_out, int out_size, void* d_ws, size_t ws_size,
                              hipStream_t stream) {
    const float* x  = (const float*)d_in[0];
    const int*   ei = (const int*)d_in[1];
    const float* W1 = (const float*)d_in[2];
    const float* b1 = (const float*)d_in[3];
    const float* W2 = (const float*)d_in[4];
    const float* b2 = (const float*)d_in[5];
    float* out = (float*)d_out;

    int N = in_sizes[0] / 128;
    int E = in_sizes[1] / 2;
    const int* row = ei;        // edge_index[0] = sources
    const int* col = ei + E;    // edge_index[1] = targets
    int NB = (N + BNODES - 1) >> BSH;          // 196 buckets (<=256 required)

    char* ws = (char*)d_ws;
    size_t o = 0;
    auto alloc = [&](size_t bytes) -> void* {
        void* p = ws + o;
        o = (o + bytes + 255) & ~(size_t)255;
        return p;
    };
    int*   bhist = (int*)alloc((size_t)(NB + 1) * 4);
    int*   bbase = (int*)alloc((size_t)(NB + 1) * 4);
    int*   bcur  = (int*)alloc((size_t)NB * 4);
    int*   off   = (int*)alloc((size_t)(N + 1) * 4);
    float* dis   = (float*)alloc((size_t)N * 4);
    int*   csr   = (int*)alloc((size_t)E * 4);
    float* xw    = (float*)alloc((size_t)N * 128 * 4);
    float* h     = (float*)alloc((size_t)N * 128 * 4);
    int2*  pairs = (int2*)h;    // alias: pairs dead before agg<128> writes h
    float* hw2   = xw;          // alias: layer-2 GEMM output (64 cols)

    zero_kernel<<<1, 256, 0, stream>>>(bhist, NB);
    hist_kernel<<<1024, 256, 0, stream>>>(col, bhist, E, NB);
    bbase_scan_kernel<<<1, 256, 0, stream>>>(bhist, bbase, bcur, NB);
    bucket_scatter_kernel<<<(E + CHUNK - 1) / CHUNK, 256, 0, stream>>>(row, col, bcur,
                                                                       pairs, E, NB);
    place_kernel<<<NB, 256, 0, stream>>>(pairs, bbase, off, dis, csr, N, NB);

    gemm_kernel<128><<<(N + 63) / 64, 256, 0, stream>>>(x, W1, xw, N);
    agg_kernel<128, true><<<(N + 3) / 4, 256, 0, stream>>>(xw, off, csr, dis, b1, h, N);
    gemm_kernel<64><<<(N + 63) / 64, 256, 0, stream>>>(h, W2, hw2, N);
    agg_kernel<64, false><<<(N + 3) / 4, 256, 0, stream>>>(hw2, off, csr, dis, b2, out, N);
}

// Round 5
// 293.452 us; speedup vs baseline: 2.0460x; 1.1908x over previous
//
#include <hip/hip_runtime.h>
#include <hip/hip_fp16.h>
#include <type_traits>

// GCN 2-layer forward: out = A( relu(A(X@W1)+b1) @ W2 ) + b2
// CSR build via 2-level LDS-staged binning (all global writes contiguous).
// Intermediates (XW1, H, HW2) stored fp16 to halve gather traffic; all
// accumulation fp32. Each layer: LDS-tiled vector-fp32 GEMM + gather-agg.

constexpr int BSH = 9;              // 512 nodes per bucket
constexpr int BNODES = 1 << BSH;
constexpr int CHUNK = 4096;         // edges per scatter block
constexpr int CAP = 12288;          // place LDS staging capacity (mean ~8200)

__global__ __launch_bounds__(256) void zero_kernel(int* __restrict__ p, int n) {
    int i = blockIdx.x * 256 + threadIdx.x;
    if (i < n) p[i] = 0;
}

__global__ __launch_bounds__(256) void hist_kernel(const int* __restrict__ col,
                                                   int* __restrict__ bhist,
                                                   int E, int NB) {
    __shared__ int lh[256];
    int t = threadIdx.x;
    lh[t] = 0;
    __syncthreads();
    for (int i = blockIdx.x * 256 + t; i < E; i += gridDim.x * 256)
        atomicAdd(&lh[col[i] >> BSH], 1);
    __syncthreads();
    if (t < NB && lh[t]) atomicAdd(&bhist[t], lh[t]);
}

__global__ __launch_bounds__(256) void bbase_scan_kernel(const int* __restrict__ bhist,
                                                         int* __restrict__ bbase,
                                                         int* __restrict__ bcur, int NB) {
    __shared__ int s[256];
    int t = threadIdx.x;
    int v = (t < NB) ? bhist[t] : 0;
    s[t] = v;
    __syncthreads();
    for (int d = 1; d < 256; d <<= 1) {
        int u = (t >= d) ? s[t - d] : 0;
        __syncthreads();
        s[t] += u;
        __syncthreads();
    }
    if (t < NB) { bbase[t] = s[t] - v; bcur[t] = s[t] - v; }
    if (t == NB - 1) bbase[NB] = s[t];
}

__global__ __launch_bounds__(256) void bucket_scatter_kernel(const int* __restrict__ row,
                                                             const int* __restrict__ col,
                                                             int* __restrict__ bcur,
                                                             int2* __restrict__ pairs,
                                                             int E, int NB) {
    __shared__ int2 sp[CHUNK];
    __shared__ int lhist[256], lofs[256], lcur[256], gbase[256];
    int t = threadIdx.x;
    int start = blockIdx.x * CHUNK;
    int cnt = min(CHUNK, E - start);
    lhist[t] = 0;
    __syncthreads();
    for (int i = t; i < cnt; i += 256)
        atomicAdd(&lhist[col[start + i] >> BSH], 1);
    __syncthreads();
    int v = lhist[t];
    lofs[t] = v;
    __syncthreads();
    for (int d = 1; d < 256; d <<= 1) {
        int u = (t >= d) ? lofs[t - d] : 0;
        __syncthreads();
        lofs[t] += u;
        __syncthreads();
    }
    int excl = lofs[t] - v;
    lofs[t] = excl;
    lcur[t] = excl;
    if (t < NB && v > 0) gbase[t] = atomicAdd(&bcur[t], v);
    __syncthreads();
    for (int i = t; i < cnt; i += 256) {
        int c = col[start + i];
        int s = row[start + i];
        int lp = atomicAdd(&lcur[c >> BSH], 1);
        sp[lp] = make_int2(s, c);
    }
    __syncthreads();
    for (int i = t; i < cnt; i += 256) {
        int2 pr = sp[i];
        int b = pr.y >> BSH;
        pairs[gbase[b] + (i - lofs[b])] = pr;
    }
}

__global__ __launch_bounds__(256) void place_kernel(const int2* __restrict__ pairs,
                                                    const int* __restrict__ bbase,
                                                    int* __restrict__ off,
                                                    float* __restrict__ dis,
                                                    int* __restrict__ csr, int N, int NB) {
    __shared__ int lhist[BNODES], lexcl[BNODES], lcur2[BNODES];
    __shared__ int sscan[256];
    __shared__ int lout[CAP];
    int b = blockIdx.x;
    int t = threadIdx.x;
    int n0 = b << BSH;
    int n1 = min(n0 + BNODES, N);
    int nn = n1 - n0;
    int base = bbase[b];
    int cnt = bbase[b + 1] - base;
    lhist[2 * t] = 0;
    lhist[2 * t + 1] = 0;
    __syncthreads();
    for (int i = t; i < cnt; i += 256)
        atomicAdd(&lhist[pairs[base + i].y - n0], 1);
    __syncthreads();
    int a0 = lhist[2 * t], a1 = lhist[2 * t + 1];
    int ps = a0 + a1;
    sscan[t] = ps;
    __syncthreads();
    for (int d = 1; d < 256; d <<= 1) {
        int u = (t >= d) ? sscan[t - d] : 0;
        __syncthreads();
        sscan[t] += u;
        __syncthreads();
    }
    int pexcl = sscan[t] - ps;
    lexcl[2 * t] = pexcl;
    lexcl[2 * t + 1] = pexcl + a0;
    lcur2[2 * t] = pexcl;
    lcur2[2 * t + 1] = pexcl + a0;
    __syncthreads();
    for (int i = t; i < nn; i += 256) {
        off[n0 + i] = base + lexcl[i];
        dis[n0 + i] = rsqrtf((float)(lhist[i] + 1));   // +1 self loop
    }
    if (b == NB - 1 && t == 0) off[N] = base + cnt;
    for (int i = t; i < cnt; i += 256) {
        int2 pr = pairs[base + i];
        int lp = atomicAdd(&lcur2[pr.y - n0], 1);
        if (lp < CAP) lout[lp] = pr.x;
        else csr[base + lp] = pr.x;
    }
    __syncthreads();
    int staged = min(cnt, CAP);
    for (int i = t; i < staged; i += 256) csr[base + i] = lout[i];
}

// Y[M,TN] (fp16) = X[M,128] (TI=float|__half) @ W[128,TN] (fp32).
template<int TN, typename TI>
__global__ __launch_bounds__(256) void gemm_kernel(const TI* __restrict__ X,
                                                   const float* __restrict__ W,
                                                   __half* __restrict__ Y, int M) {
    constexpr int K = 128, KC = 32, TM = 64;
    constexpr int CPT = TN / 16;
    __shared__ float As[KC][TM + 8];
    __shared__ float Bs[KC][TN];
    int tid = threadIdx.x;
    int row0 = blockIdx.x * TM;
    int tx = tid & 15, ty = tid >> 4;
    float acc[4][CPT];
#pragma unroll
    for (int i = 0; i < 4; ++i)
#pragma unroll
        for (int j = 0; j < CPT; ++j) acc[i][j] = 0.0f;

    for (int k0 = 0; k0 < K; k0 += KC) {
        if constexpr (std::is_same<TI, float>::value) {
#pragma unroll
            for (int j = 0; j < 2; ++j) {
                int l = tid + 256 * j;               // 0..511
                int r = l >> 3;
                int kq = l & 7;
                int row = row0 + r;
                float4 v = make_float4(0.f, 0.f, 0.f, 0.f);
                if (row < M) v = *(const float4*)(X + (size_t)row * K + k0 + kq * 4);
                As[kq * 4 + 0][r] = v.x;
                As[kq * 4 + 1][r] = v.y;
                As[kq * 4 + 2][r] = v.z;
                As[kq * 4 + 3][r] = v.w;
            }
        } else {
            int r = tid >> 2;                        // 0..63
            int kq = tid & 3;                        // 4 x 8 halfs = 32 k
            int row = row0 + r;
            uint4 u = make_uint4(0, 0, 0, 0);
            if (row < M) u = *(const uint4*)(X + (size_t)row * K + k0 + kq * 8);
            const unsigned int uu[4] = {u.x, u.y, u.z, u.w};
#pragma unroll
            for (int q = 0; q < 4; ++q) {
                __half2 hv = *reinterpret_cast<const __half2*>(&uu[q]);
                float2 f = __half22float2(hv);
                As[kq * 8 + 2 * q + 0][r] = f.x;
                As[kq * 8 + 2 * q + 1][r] = f.y;
            }
        }
#pragma unroll
        for (int j = 0; j < KC * TN / 1024; ++j) {
            int l = tid + 256 * j;
            int kk = l / (TN / 4);
            int cq = l % (TN / 4);
            *(float4*)&Bs[kk][cq * 4] = *(const float4*)(W + (size_t)(k0 + kk) * TN + cq * 4);
        }
        __syncthreads();
#pragma unroll
        for (int kk = 0; kk < KC; ++kk) {
            float4 av = *(const float4*)&As[kk][ty * 4];
            float a[4] = {av.x, av.y, av.z, av.w};
            float b[CPT];
#pragma unroll
            for (int q = 0; q < CPT / 4; ++q) {
                float4 bv = *(const float4*)&Bs[kk][tx * CPT + q * 4];
                b[q * 4 + 0] = bv.x; b[q * 4 + 1] = bv.y;
                b[q * 4 + 2] = bv.z; b[q * 4 + 3] = bv.w;
            }
#pragma unroll
            for (int i = 0; i < 4; ++i)
#pragma unroll
                for (int j = 0; j < CPT; ++j) acc[i][j] = fmaf(a[i], b[j], acc[i][j]);
        }
        __syncthreads();
    }
#pragma unroll
    for (int i = 0; i < 4; ++i) {
        int row = row0 + ty * 4 + i;
        if (row < M) {
            __half2 hv[CPT / 2];
#pragma unroll
            for (int q = 0; q < CPT / 2; ++q)
                hv[q] = __float22half2_rn(make_float2(acc[i][2 * q], acc[i][2 * q + 1]));
            *(uint2*)(Y + (size_t)row * TN + tx * CPT) = *reinterpret_cast<uint2*>(&hv[0]);
            if constexpr (CPT == 8)
                *(uint2*)(Y + (size_t)row * TN + tx * CPT + 4) =
                    *reinterpret_cast<uint2*>(&hv[2]);
        }
    }
}

// out[v] = sum_{e} dis[src]*dis[v]*H[src] + dis[v]^2*H[v] + b, opt relu.
// H fp16; accumulate fp32; TOUT fp16 (mid layer) or fp32 (final).
// One wave per node; 4 nodes per 256-thread block; 8 edges in flight.
template<int C, bool RELU, typename TOUT>
__global__ __launch_bounds__(256) void agg_kernel(const __half* __restrict__ H,
                                                  const int* __restrict__ off,
                                                  const int* __restrict__ src,
                                                  const float* __restrict__ dis,
                                                  const float* __restrict__ bias,
                                                  TOUT* __restrict__ out, int N) {
    int node = blockIdx.x * 4 + (threadIdx.x >> 6);
    if (node >= N) return;
    int lane = threadIdx.x & 63;
    constexpr int F = C / 64;                    // halves per lane (2 or 1)
    float dv = dis[node];
    float acc0 = 0.f, acc1 = 0.f;
    {
        float sw = dv * dv;
        if constexpr (F == 2) {
            float2 f = __half22float2(*(const __half2*)(H + (size_t)node * C + lane * 2));
            acc0 = sw * f.x; acc1 = sw * f.y;
        } else {
            acc0 = sw * __half2float(H[(size_t)node * C + lane]);
        }
    }
    int e = off[node], e1 = off[node + 1];
    for (; e + 8 <= e1; e += 8) {
        int s[8];
#pragma unroll
        for (int k = 0; k < 8; ++k) s[k] = src[e + k];
        float w[8];
#pragma unroll
        for (int k = 0; k < 8; ++k) w[k] = dis[s[k]] * dv;
        if constexpr (F == 2) {
            __half2 v[8];
#pragma unroll
            for (int k = 0; k < 8; ++k)
                v[k] = *(const __half2*)(H + (size_t)s[k] * C + lane * 2);
#pragma unroll
            for (int k = 0; k < 8; ++k) {
                float2 f = __half22float2(v[k]);
                acc0 = fmaf(w[k], f.x, acc0);
                acc1 = fmaf(w[k], f.y, acc1);
            }
        } else {
            __half v[8];
#pragma unroll
            for (int k = 0; k < 8; ++k) v[k] = H[(size_t)s[k] * C + lane];
#pragma unroll
            for (int k = 0; k < 8; ++k) acc0 = fmaf(w[k], __half2float(v[k]), acc0);
        }
    }
    for (; e < e1; ++e) {
        int s = src[e];
        float w = dis[s] * dv;
        if constexpr (F == 2) {
            float2 f = __half22float2(*(const __half2*)(H + (size_t)s * C + lane * 2));
            acc0 = fmaf(w, f.x, acc0);
            acc1 = fmaf(w, f.y, acc1);
        } else {
            acc0 = fmaf(w, __half2float(H[(size_t)s * C + lane]), acc0);
        }
    }
    if constexpr (F == 2) {
        float r0 = acc0 + bias[lane * 2 + 0];
        float r1 = acc1 + bias[lane * 2 + 1];
        if (RELU) { r0 = fmaxf(r0, 0.f); r1 = fmaxf(r1, 0.f); }
        if constexpr (std::is_same<TOUT, __half>::value) {
            *(__half2*)(out + (size_t)node * C + lane * 2) =
                __float22half2_rn(make_float2(r0, r1));
        } else {
            out[(size_t)node * C + lane * 2 + 0] = r0;
            out[(size_t)node * C + lane * 2 + 1] = r1;
        }
    } else {
        float r0 = acc0 + bias[lane];
        if (RELU) r0 = fmaxf(r0, 0.f);
        if constexpr (std::is_same<TOUT, __half>::value)
            out[(size_t)node * C + lane] = __float2half_rn(r0);
        else
            out[(size_t)node * C + lane] = r0;
    }
}

extern "C" void kernel_launch(void* const* d_in, const int* in_sizes, int n_in,
                              void* d_out, int out_size, void* d_ws, size_t ws_size,
                              hipStream_t stream) {
    const float* x  = (const float*)d_in[0];
    const int*   ei = (const int*)d_in[1];
    const float* W1 = (const float*)d_in[2];
    const float* b1 = (const float*)d_in[3];
    const float* W2 = (const float*)d_in[4];
    const float* b2 = (const float*)d_in[5];
    float* out = (float*)d_out;

    int N = in_sizes[0] / 128;
    int E = in_sizes[1] / 2;
    const int* row = ei;        // edge_index[0] = sources
    const int* col = ei + E;    // edge_index[1] = targets
    int NB = (N + BNODES - 1) >> BSH;

    char* ws = (char*)d_ws;
    size_t o = 0;
    auto alloc = [&](size_t bytes) -> void* {
        void* p = ws + o;
        o = (o + bytes + 255) & ~(size_t)255;
        return p;
    };
    int*    bhist = (int*)alloc((size_t)(NB + 1) * 4);
    int*    bbase = (int*)alloc((size_t)(NB + 1) * 4);
    int*    bcur  = (int*)alloc((size_t)NB * 4);
    int*    off   = (int*)alloc((size_t)(N + 1) * 4);
    float*  dis   = (float*)alloc((size_t)N * 4);
    int*    csr   = (int*)alloc((size_t)E * 4);
    __half* xw    = (__half*)alloc((size_t)N * 128 * 2);
    __half* h     = (__half*)alloc((size_t)N * 128 * 2);
    int2*   pairs = (int2*)alloc((size_t)E * 8);   // dead after place_kernel
    __half* hw2   = xw;          // alias: layer-2 GEMM output (64 cols fp16)

    zero_kernel<<<1, 256, 0, stream>>>(bhist, NB);
    hist_kernel<<<1024, 256, 0, stream>>>(col, bhist, E, NB);
    bbase_scan_kernel<<<1, 256, 0, stream>>>(bhist, bbase, bcur, NB);
    bucket_scatter_kernel<<<(E + CHUNK - 1) / CHUNK, 256, 0, stream>>>(row, col, bcur,
                                                                       pairs, E, NB);
    place_kernel<<<NB, 256, 0, stream>>>(pairs, bbase, off, dis, csr, N, NB);

    gemm_kernel<128, float><<<(N + 63) / 64, 256, 0, stream>>>(x, W1, xw, N);
    agg_kernel<128, true, __half><<<(N + 3) / 4, 256, 0, stream>>>(xw, off, csr, dis,
                                                                   b1, h, N);
    gemm_kernel<64, __half><<<(N + 63) / 64, 256, 0, stream>>>(h, W2, hw2, N);
    agg_kernel<64, false, float><<<(N + 3) / 4, 256, 0, stream>>>(hw2, off, csr, dis,
                                                                  b2, out, N);
}

// Round 6
// 245.087 us; speedup vs baseline: 2.4497x; 1.1973x over previous
//
#include <hip/hip_runtime.h>
#include <hip/hip_fp16.h>
#include <type_traits>

// GCN 2-layer forward: out = A( relu(A(X@W1)+b1) @ W2 ) + b2
// CSR build via 2-level LDS-staged binning. Intermediates fp16.
// Source-side deg^-1/2 folded into GEMM epilogue (H' = dis*XW), so the
// aggregation does ONE random row-load per edge: out[v]=dv*(sum H'[s]+H'[v])+b.
// Agg: 2 nodes/wave (32 lanes each), 8 edges in flight, masked tail.

constexpr int BSH = 9;              // 512 nodes per bucket
constexpr int BNODES = 1 << BSH;
constexpr int CHUNK = 4096;         // edges per scatter block
constexpr int CAP = 12288;          // place LDS staging capacity (mean ~8200)

__global__ __launch_bounds__(256) void zero_kernel(int* __restrict__ p, int n) {
    int i = blockIdx.x * 256 + threadIdx.x;
    if (i < n) p[i] = 0;
}

__global__ __launch_bounds__(256) void hist_kernel(const int* __restrict__ col,
                                                   int* __restrict__ bhist,
                                                   int E, int NB) {
    __shared__ int lh[256];
    int t = threadIdx.x;
    lh[t] = 0;
    __syncthreads();
    for (int i = blockIdx.x * 256 + t; i < E; i += gridDim.x * 256)
        atomicAdd(&lh[col[i] >> BSH], 1);
    __syncthreads();
    if (t < NB && lh[t]) atomicAdd(&bhist[t], lh[t]);
}

__global__ __launch_bounds__(256) void bbase_scan_kernel(const int* __restrict__ bhist,
                                                         int* __restrict__ bbase,
                                                         int* __restrict__ bcur, int NB) {
    __shared__ int s[256];
    int t = threadIdx.x;
    int v = (t < NB) ? bhist[t] : 0;
    s[t] = v;
    __syncthreads();
    for (int d = 1; d < 256; d <<= 1) {
        int u = (t >= d) ? s[t - d] : 0;
        __syncthreads();
        s[t] += u;
        __syncthreads();
    }
    if (t < NB) { bbase[t] = s[t] - v; bcur[t] = s[t] - v; }
    if (t == NB - 1) bbase[NB] = s[t];
}

__global__ __launch_bounds__(256) void bucket_scatter_kernel(const int* __restrict__ row,
                                                             const int* __restrict__ col,
                                                             int* __restrict__ bcur,
                                                             int2* __restrict__ pairs,
                                                             int E, int NB) {
    __shared__ int2 sp[CHUNK];
    __shared__ int lhist[256], lofs[256], lcur[256], gbase[256];
    int t = threadIdx.x;
    int start = blockIdx.x * CHUNK;
    int cnt = min(CHUNK, E - start);
    lhist[t] = 0;
    __syncthreads();
    for (int i = t; i < cnt; i += 256)
        atomicAdd(&lhist[col[start + i] >> BSH], 1);
    __syncthreads();
    int v = lhist[t];
    lofs[t] = v;
    __syncthreads();
    for (int d = 1; d < 256; d <<= 1) {
        int u = (t >= d) ? lofs[t - d] : 0;
        __syncthreads();
        lofs[t] += u;
        __syncthreads();
    }
    int excl = lofs[t] - v;
    lofs[t] = excl;
    lcur[t] = excl;
    if (t < NB && v > 0) gbase[t] = atomicAdd(&bcur[t], v);
    __syncthreads();
    for (int i = t; i < cnt; i += 256) {
        int c = col[start + i];
        int s = row[start + i];
        int lp = atomicAdd(&lcur[c >> BSH], 1);
        sp[lp] = make_int2(s, c);
    }
    __syncthreads();
    for (int i = t; i < cnt; i += 256) {
        int2 pr = sp[i];
        int b = pr.y >> BSH;
        pairs[gbase[b] + (i - lofs[b])] = pr;
    }
}

__global__ __launch_bounds__(256) void place_kernel(const int2* __restrict__ pairs,
                                                    const int* __restrict__ bbase,
                                                    int* __restrict__ off,
                                                    float* __restrict__ dis,
                                                    int* __restrict__ csr, int N, int NB) {
    __shared__ int lhist[BNODES], lexcl[BNODES], lcur2[BNODES];
    __shared__ int sscan[256];
    __shared__ int lout[CAP];
    int b = blockIdx.x;
    int t = threadIdx.x;
    int n0 = b << BSH;
    int n1 = min(n0 + BNODES, N);
    int nn = n1 - n0;
    int base = bbase[b];
    int cnt = bbase[b + 1] - base;
    lhist[2 * t] = 0;
    lhist[2 * t + 1] = 0;
    __syncthreads();
    for (int i = t; i < cnt; i += 256)
        atomicAdd(&lhist[pairs[base + i].y - n0], 1);
    __syncthreads();
    int a0 = lhist[2 * t], a1 = lhist[2 * t + 1];
    int ps = a0 + a1;
    sscan[t] = ps;
    __syncthreads();
    for (int d = 1; d < 256; d <<= 1) {
        int u = (t >= d) ? sscan[t - d] : 0;
        __syncthreads();
        sscan[t] += u;
        __syncthreads();
    }
    int pexcl = sscan[t] - ps;
    lexcl[2 * t] = pexcl;
    lexcl[2 * t + 1] = pexcl + a0;
    lcur2[2 * t] = pexcl;
    lcur2[2 * t + 1] = pexcl + a0;
    __syncthreads();
    for (int i = t; i < nn; i += 256) {
        off[n0 + i] = base + lexcl[i];
        dis[n0 + i] = rsqrtf((float)(lhist[i] + 1));   // +1 self loop
    }
    if (b == NB - 1 && t == 0) off[N] = base + cnt;
    for (int i = t; i < cnt; i += 256) {
        int2 pr = pairs[base + i];
        int lp = atomicAdd(&lcur2[pr.y - n0], 1);
        if (lp < CAP) lout[lp] = pr.x;
        else csr[base + lp] = pr.x;
    }
    __syncthreads();
    int staged = min(cnt, CAP);
    for (int i = t; i < staged; i += 256) csr[base + i] = lout[i];
}

// Y[M,TN] (fp16) = dis[row] * (X[M,128] @ W[128,TN]).  X: float | __half.
template<int TN, typename TI>
__global__ __launch_bounds__(256) void gemm_kernel(const TI* __restrict__ X,
                                                   const float* __restrict__ W,
                                                   const float* __restrict__ dis,
                                                   __half* __restrict__ Y, int M) {
    constexpr int K = 128, KC = 32, TM = 64;
    constexpr int CPT = TN / 16;
    __shared__ float As[KC][TM + 8];
    __shared__ float Bs[KC][TN];
    int tid = threadIdx.x;
    int row0 = blockIdx.x * TM;
    int tx = tid & 15, ty = tid >> 4;
    float acc[4][CPT];
#pragma unroll
    for (int i = 0; i < 4; ++i)
#pragma unroll
        for (int j = 0; j < CPT; ++j) acc[i][j] = 0.0f;

    for (int k0 = 0; k0 < K; k0 += KC) {
        if constexpr (std::is_same<TI, float>::value) {
#pragma unroll
            for (int j = 0; j < 2; ++j) {
                int l = tid + 256 * j;               // 0..511
                int r = l >> 3;
                int kq = l & 7;
                int row = row0 + r;
                float4 v = make_float4(0.f, 0.f, 0.f, 0.f);
                if (row < M) v = *(const float4*)(X + (size_t)row * K + k0 + kq * 4);
                As[kq * 4 + 0][r] = v.x;
                As[kq * 4 + 1][r] = v.y;
                As[kq * 4 + 2][r] = v.z;
                As[kq * 4 + 3][r] = v.w;
            }
        } else {
            int r = tid >> 2;                        // 0..63
            int kq = tid & 3;                        // 4 x 8 halfs = 32 k
            int row = row0 + r;
            uint4 u = make_uint4(0, 0, 0, 0);
            if (row < M) u = *(const uint4*)(X + (size_t)row * K + k0 + kq * 8);
            const unsigned int uu[4] = {u.x, u.y, u.z, u.w};
#pragma unroll
            for (int q = 0; q < 4; ++q) {
                __half2 hv = *reinterpret_cast<const __half2*>(&uu[q]);
                float2 f = __half22float2(hv);
                As[kq * 8 + 2 * q + 0][r] = f.x;
                As[kq * 8 + 2 * q + 1][r] = f.y;
            }
        }
#pragma unroll
        for (int j = 0; j < KC * TN / 1024; ++j) {
            int l = tid + 256 * j;
            int kk = l / (TN / 4);
            int cq = l % (TN / 4);
            *(float4*)&Bs[kk][cq * 4] = *(const float4*)(W + (size_t)(k0 + kk) * TN + cq * 4);
        }
        __syncthreads();
#pragma unroll
        for (int kk = 0; kk < KC; ++kk) {
            float4 av = *(const float4*)&As[kk][ty * 4];
            float a[4] = {av.x, av.y, av.z, av.w};
            float b[CPT];
#pragma unroll
            for (int q = 0; q < CPT / 4; ++q) {
                float4 bv = *(const float4*)&Bs[kk][tx * CPT + q * 4];
                b[q * 4 + 0] = bv.x; b[q * 4 + 1] = bv.y;
                b[q * 4 + 2] = bv.z; b[q * 4 + 3] = bv.w;
            }
#pragma unroll
            for (int i = 0; i < 4; ++i)
#pragma unroll
                for (int j = 0; j < CPT; ++j) acc[i][j] = fmaf(a[i], b[j], acc[i][j]);
        }
        __syncthreads();
    }
#pragma unroll
    for (int i = 0; i < 4; ++i) {
        int row = row0 + ty * 4 + i;
        if (row < M) {
            float sc = dis[row];
            __half2 hv[CPT / 2];
#pragma unroll
            for (int q = 0; q < CPT / 2; ++q)
                hv[q] = __float22half2_rn(make_float2(sc * acc[i][2 * q],
                                                      sc * acc[i][2 * q + 1]));
            *(uint2*)(Y + (size_t)row * TN + tx * CPT) = *reinterpret_cast<uint2*>(&hv[0]);
            if constexpr (CPT == 8)
                *(uint2*)(Y + (size_t)row * TN + tx * CPT + 4) =
                    *reinterpret_cast<uint2*>(&hv[2]);
        }
    }
}

// out[v] = dv*( sum_{e} Hs[src] + Hs[v] ) + b  (Hs pre-scaled by dis), opt relu.
// 2 nodes per wave (32 lanes each); 8 edges in flight; masked tail.
template<int C, bool RELU, typename TOUT>
__global__ __launch_bounds__(256) void agg_kernel(const __half* __restrict__ Hs,
                                                  const int* __restrict__ off,
                                                  const int* __restrict__ src,
                                                  const float* __restrict__ dis,
                                                  const float* __restrict__ bias,
                                                  TOUT* __restrict__ out, int N) {
    constexpr int HPL = C / 32;                  // halfs per lane: 4 or 2
    int node = blockIdx.x * 8 + (threadIdx.x >> 5);
    if (node >= N) return;
    int lane = threadIdx.x & 31;
    float dv = dis[node];
    float acc[HPL];
    {   // self term (Hs[v] = dis[v]*row)
        const __half* hp = Hs + (size_t)node * C + lane * HPL;
        if constexpr (HPL == 4) {
            uint2 u = *(const uint2*)hp;
            float2 f0 = __half22float2(*reinterpret_cast<__half2*>(&u.x));
            float2 f1 = __half22float2(*reinterpret_cast<__half2*>(&u.y));
            acc[0] = f0.x; acc[1] = f0.y; acc[2] = f1.x; acc[3] = f1.y;
        } else {
            float2 f0 = __half22float2(*(const __half2*)hp);
            acc[0] = f0.x; acc[1] = f0.y;
        }
    }
    int e0 = off[node], e1 = off[node + 1];
    for (int e = e0; e < e1; e += 8) {
        int s[8];
        float w[8];
#pragma unroll
        for (int k = 0; k < 8; ++k) {
            int idx = (e + k < e1) ? e + k : e1 - 1;
            s[k] = src[idx];
            w[k] = (e + k < e1) ? 1.0f : 0.0f;
        }
        if constexpr (HPL == 4) {
            uint2 v[8];
#pragma unroll
            for (int k = 0; k < 8; ++k)
                v[k] = *(const uint2*)(Hs + (size_t)s[k] * C + lane * 4);
#pragma unroll
            for (int k = 0; k < 8; ++k) {
                float2 f0 = __half22float2(*reinterpret_cast<__half2*>(&v[k].x));
                float2 f1 = __half22float2(*reinterpret_cast<__half2*>(&v[k].y));
                acc[0] = fmaf(w[k], f0.x, acc[0]);
                acc[1] = fmaf(w[k], f0.y, acc[1]);
                acc[2] = fmaf(w[k], f1.x, acc[2]);
                acc[3] = fmaf(w[k], f1.y, acc[3]);
            }
        } else {
            unsigned int v[8];
#pragma unroll
            for (int k = 0; k < 8; ++k)
                v[k] = *(const unsigned int*)(Hs + (size_t)s[k] * C + lane * 2);
#pragma unroll
            for (int k = 0; k < 8; ++k) {
                float2 f0 = __half22float2(*reinterpret_cast<__half2*>(&v[k]));
                acc[0] = fmaf(w[k], f0.x, acc[0]);
                acc[1] = fmaf(w[k], f0.y, acc[1]);
            }
        }
    }
    float r[HPL];
#pragma unroll
    for (int f = 0; f < HPL; ++f) {
        r[f] = fmaf(dv, acc[f], bias[lane * HPL + f]);
        if (RELU) r[f] = fmaxf(r[f], 0.0f);
    }
    if constexpr (std::is_same<TOUT, __half>::value) {
        __half2 hv[HPL / 2];
#pragma unroll
        for (int q = 0; q < HPL / 2; ++q)
            hv[q] = __float22half2_rn(make_float2(r[2 * q], r[2 * q + 1]));
        if constexpr (HPL == 4)
            *(uint2*)(out + (size_t)node * C + lane * 4) = *reinterpret_cast<uint2*>(&hv[0]);
        else
            *(unsigned int*)(out + (size_t)node * C + lane * 2) =
                *reinterpret_cast<unsigned int*>(&hv[0]);
    } else {
        if constexpr (HPL == 4) {
            *(float4*)(out + (size_t)node * C + lane * 4) =
                make_float4(r[0], r[1], r[2], r[3]);
        } else {
            *(float2*)(out + (size_t)node * C + lane * 2) = make_float2(r[0], r[1]);
        }
    }
}

extern "C" void kernel_launch(void* const* d_in, const int* in_sizes, int n_in,
                              void* d_out, int out_size, void* d_ws, size_t ws_size,
                              hipStream_t stream) {
    const float* x  = (const float*)d_in[0];
    const int*   ei = (const int*)d_in[1];
    const float* W1 = (const float*)d_in[2];
    const float* b1 = (const float*)d_in[3];
    const float* W2 = (const float*)d_in[4];
    const float* b2 = (const float*)d_in[5];
    float* out = (float*)d_out;

    int N = in_sizes[0] / 128;
    int E = in_sizes[1] / 2;
    const int* row = ei;        // edge_index[0] = sources
    const int* col = ei + E;    // edge_index[1] = targets
    int NB = (N + BNODES - 1) >> BSH;

    char* ws = (char*)d_ws;
    size_t o = 0;
    auto alloc = [&](size_t bytes) -> void* {
        void* p = ws + o;
        o = (o + bytes + 255) & ~(size_t)255;
        return p;
    };
    int*    bhist = (int*)alloc((size_t)(NB + 1) * 4);
    int*    bbase = (int*)alloc((size_t)(NB + 1) * 4);
    int*    bcur  = (int*)alloc((size_t)NB * 4);
    int*    off   = (int*)alloc((size_t)(N + 1) * 4);
    float*  dis   = (float*)alloc((size_t)N * 4);
    int*    csr   = (int*)alloc((size_t)E * 4);
    __half* xw    = (__half*)alloc((size_t)N * 128 * 2);   // dis*(X@W1)
    __half* h     = (__half*)alloc((size_t)N * 128 * 2);   // relu activations
    int2*   pairs = (int2*)alloc((size_t)E * 8);           // dead after place
    __half* hw2   = xw;          // alias: dis*(h@W2), 64 cols fp16

    zero_kernel<<<1, 256, 0, stream>>>(bhist, NB);
    hist_kernel<<<1024, 256, 0, stream>>>(col, bhist, E, NB);
    bbase_scan_kernel<<<1, 256, 0, stream>>>(bhist, bbase, bcur, NB);
    bucket_scatter_kernel<<<(E + CHUNK - 1) / CHUNK, 256, 0, stream>>>(row, col, bcur,
                                                                       pairs, E, NB);
    place_kernel<<<NB, 256, 0, stream>>>(pairs, bbase, off, dis, csr, N, NB);

    gemm_kernel<128, float><<<(N + 63) / 64, 256, 0, stream>>>(x, W1, dis, xw, N);
    agg_kernel<128, true, __half><<<(N + 7) / 8, 256, 0, stream>>>(xw, off, csr, dis,
                                                                   b1, h, N);
    gemm_kernel<64, __half><<<(N + 63) / 64, 256, 0, stream>>>(h, W2, dis, hw2, N);
    agg_kernel<64, false, float><<<(N + 7) / 8, 256, 0, stream>>>(hw2, off, csr, dis,
                                                                  b2, out, N);
}